// Round 17
// baseline (339.406 us; speedup 1.0000x reference)
//
#include <hip/hip_runtime.h>
#include <hip/hip_bf16.h>
#include <math.h>

// Problem constants (fixed by setup_inputs)
#define BB 128
#define DD 512
#define HH 1024
#define NB 32     // num_coeff_per_dim
#define MM 63     // 2N-1 simpson points
#define TT 16
#define ITERS 10

// ws layout (float units)
#define OFF_U       0        // 32 fp32
#define OFF_TTRUE   64       // 64 fp32 (tt[63]=0)
#define OFF_PHIOUT  128      // 512 fp32
#define OFF_PHIF_BF 1024     // bf16 [64 m][32 n]  (row 63 = 0)   = 1024 floats
#define OFF_QT_BF   2048     // bf16 [32 j][64 m]  (col 63 = 0)   = 1024 floats
#define HDRF        4096
#define OFF_PTPA    HDRF                     // bf16 frag-packed [B][32 hs][2 mt][64][8] = 2097152 f
#define OFF_PTP0    (OFF_PTPA + 2097152)     // bf16 frag-packed ping-pong buffer       = 2097152 f
#define OFF_W1P     (OFF_PTP0 + 2097152)     // bf16 frag-packed [64 hb][16 ds][64][8] = 262144 f
#define OFF_W2P     (OFF_W1P + 262144)       // bf16 frag-packed [32 db][32 hs][64][8] = 262144 f
#define OFF_WWP     (OFF_W2P + 262144)       // bf16 frag-packed [64 h2b][32 hs][64][8] = 524288 f
#define OFF_YW1     (OFF_WWP + 524288)       // fp32 [128 b][1024 h2] = 131072 f
// end = 5378048 floats = 21.5 MB

typedef __attribute__((ext_vector_type(8))) short bf16x8;
typedef __attribute__((ext_vector_type(4))) float f32x4;

static __device__ __forceinline__ unsigned short f2bf(float f) {
    unsigned int x = __builtin_bit_cast(unsigned int, f);
    unsigned int r = x + 0x7FFFu + ((x >> 16) & 1u);   // RNE
    return (unsigned short)(r >> 16);
}

static __device__ __forceinline__ void store4bf(unsigned short* p,
                                                float v0, float v1, float v2, float v3) {
    unsigned int lo = (unsigned int)f2bf(v0) | ((unsigned int)f2bf(v1) << 16);
    unsigned int hi = (unsigned int)f2bf(v2) | ((unsigned int)f2bf(v3) << 16);
    uint2 u; u.x = lo; u.y = hi;
    *(uint2*)p = u;   // 8B-aligned by construction
}

static __device__ __forceinline__ float tanh_fast(float x) {
    float e = exp2f(x * 2.88539008177793f);   // 2*log2(e)
    return 1.0f - 2.0f / (e + 1.0f);
}

// XOR-swizzled LDS A-tile addressing: tile [32 r][512 c] bf16, linear 32KB,
// byte = (r*1024 + c*2) ^ ((r&7)<<4). Bijective per row, 16B-aligned b128.
static __device__ __forceinline__ unsigned short* aS(unsigned short* smA, int r, int c16) {
    return (unsigned short*)((char*)smA + (((r << 10) + (c16 << 4)) ^ ((r & 7) << 4)));
}

// ---------------------------------------------------------------------------
// PROLOGUE (single dispatch, blocks partitioned by role):
//   bid 0        : setup -- closed-form DCT-I Phi_inv (no GJ)
//   bid 1..64    : pack_w1   (hb = bid-1)
//   bid 65..96   : pack_w2   (db = bid-65)
//   bid 97..352  : pack_ww   (idx: h2grp = idx&31, hpb = (idx>>5)*4+w)
//   bid 353..384 : yw1       (h2grp = bid-353, waves = b-tiles)
// ---------------------------------------------------------------------------
__global__ __launch_bounds__(256) void prologue_kernel(
        const float* __restrict__ t_span, const float* __restrict__ W1,
        const float* __restrict__ W2, const float* __restrict__ y_init,
        float* __restrict__ ws) {
    __shared__ __align__(16) char smem[66560];
    const int bid  = blockIdx.x;
    const int t    = threadIdx.x;
    const int lane = t & 63;
    const int w    = t >> 6;
    const int q    = lane >> 4;
    const int l15  = lane & 15;

    if (bid == 0) {
        // ---------------- setup ----------------
        double* tsim    = (double*)(smem + 0);       // 63
        double* ttrue_d = (double*)(smem + 512);     // 63
        double* wid     = (double*)(smem + 1024);    // 31
        double* phid    = (double*)(smem + 1280);    // 32*63
        double* pinv    = (double*)(smem + 17408);   // 32*32 closed-form Phi_inv
        double* Rl      = (double*)(smem + 34048);   // 63*32
        double* Qd      = (double*)(smem + 50176);   // 63*32

        const double PI = 3.14159265358979323846;
        const double t0 = (double)t_span[0];
        const double t1 = (double)t_span[TT - 1];

        if (t < MM) {
            double v;
            if ((t & 1) == 0) {
                int j = t >> 1;
                v = -cos(PI * (double)j / (double)(NB - 1));
            } else {
                int i = t >> 1;
                double a = -cos(PI * (double)i / (double)(NB - 1));
                double b = -cos(PI * (double)(i + 1) / (double)(NB - 1));
                v = 0.5 * (a + b);
            }
            tsim[t] = v;
            ttrue_d[t] = t0 + 0.5 * (t1 - t0) * (v + 1.0);
        }
        __syncthreads();
        if (t < 31) wid[t] = (ttrue_d[2 * t + 2] - ttrue_d[2 * t]) / 6.0;
        if (t < MM) ws[OFF_TTRUE + t] = (float)ttrue_d[t];
        if (t == 63) ws[OFF_TTRUE + 63] = 0.0f;

        if (t < MM) {
            double x = tsim[t];
            double r0 = 1.0, r1 = x;
            phid[0 * MM + t] = r0;
            phid[1 * MM + t] = r1;
            for (int n = 2; n < NB; n++) {
                double r2 = 2.0 * x * r1 - r0;
                phid[n * MM + t] = r2;
                r0 = r1; r1 = r2;
            }
        }

        // closed-form Phi_inv (independent of phid)
        for (int f = t; f < NB * NB; f += 256) {
            int i = f >> 5, j = f & 31;
            double ci = (i == 0 || i == NB - 1) ? 2.0 : 1.0;
            double cj = (j == 0 || j == NB - 1) ? 2.0 : 1.0;
            double v = 2.0 * cos(PI * (double)(i * j) / (double)(NB - 1))
                       / ((double)(NB - 1) * ci * cj);
            pinv[f] = (j & 1) ? -v : v;
        }
        __syncthreads();

        {   // phif_bf [m 64][n 32], row 63 = 0
            unsigned short* pf = (unsigned short*)(ws + OFF_PHIF_BF);
            for (int f = t; f < 64 * 32; f += 256) {
                int m = f >> 5, n = f & 31;
                pf[f] = f2bf(m < MM ? (float)phid[n * MM + m] : 0.0f);
            }
        }

        if (t < MM) {
            double acc = 0.0;
            Rl[t * NB + 0] = 0.0;
            for (int i = 1; i < NB; i++) {
                int ip = i - 1;
                double wv = 0.0;
                if (t == 2 * ip)     wv += wid[ip];
                if (t == 2 * ip + 1) wv += 4.0 * wid[ip];
                if (t == 2 * ip + 2) wv += wid[ip];
                acc += wv;
                Rl[t * NB + i] = acc;
            }
        }
        __syncthreads();

        for (int f = t; f < MM * NB; f += 256) {
            int m = f >> 5, j = f & 31;
            double s = 0.0;
            for (int i = 0; i < NB; i++) s += Rl[m * NB + i] * pinv[i * 32 + j];
            Qd[f] = s;
        }
        __syncthreads();

        {   // qt_bf [j 32][m 64], col 63 = 0
            unsigned short* qt = (unsigned short*)(ws + OFF_QT_BF);
            for (int f = t; f < 32 * 64; f += 256) {
                int j = f >> 6, m = f & 63;
                qt[f] = f2bf(m < MM ? (float)Qd[m * NB + j] : 0.0f);
            }
        }
        if (t < NB) {
            double s = 0.0;
            for (int i = 0; i < NB; i++) s += pinv[i * 32 + t];
            ws[OFF_U + t] = (float)s;
        }
        if (t < TT) {
            double x = -1.0 + 2.0 * ((double)t_span[t] - t0) / (t1 - t0);
            double r0 = 1.0, r1 = x;
            ws[OFF_PHIOUT + 0 * TT + t] = 1.0f;
            ws[OFF_PHIOUT + 1 * TT + t] = (float)x;
            for (int n = 2; n < NB; n++) {
                double r2 = 2.0 * x * r1 - r0;
                ws[OFF_PHIOUT + n * TT + t] = (float)r2;
                r0 = r1; r1 = r2;
            }
        }
        return;
    }

    if (bid <= 64) {
        // ---------------- pack_w1: hb = bid-1 ----------------
        unsigned short* W1p = (unsigned short*)(ws + OFF_W1P);
        const int hb = bid - 1;
        #pragma unroll
        for (int i = 0; i < 4; i++) {
            int f = i * 256 + t;
            int ds = f >> 6, ln = f & 63;
            int qq = ln >> 4, ll = ln & 15;
            unsigned short tmp[8];
            #pragma unroll
            for (int e = 0; e < 8; e++)
                tmp[e] = f2bf(W1[(size_t)(ds * 32 + qq * 8 + e) * HH + hb * 16 + ll]);
            *(uint4*)(W1p + ((size_t)(hb * 16 + ds) * 64 + ln) * 8) = *(uint4*)tmp;
        }
        return;
    }

    if (bid <= 96) {
        // ---------------- pack_w2: db = bid-65 ----------------
        unsigned short* W2p = (unsigned short*)(ws + OFF_W2P);
        const int db = bid - 65;
        #pragma unroll
        for (int i = 0; i < 8; i++) {
            int f = i * 256 + t;
            int hs = f >> 6, ln = f & 63;
            int qq = ln >> 4, ll = ln & 15;
            unsigned short tmp[8];
            #pragma unroll
            for (int e = 0; e < 8; e++)
                tmp[e] = f2bf(W2[(size_t)(hs * 32 + qq * 8 + e) * DD + db * 16 + ll]);
            *(uint4*)(W2p + ((size_t)(db * 32 + hs) * 64 + ln) * 8) = *(uint4*)tmp;
        }
        return;
    }

    // lw1t = bf16 TRANSPOSED W1 slice: [32 col][520 row-stride] = 33280 B.
    unsigned short* lw1t = (unsigned short*)smem;

    if (bid <= 352) {
        // ---------------- pack_ww: WW = bf16(W2bf . W1bf), frag-packed ----
        unsigned short* WWp = (unsigned short*)(ws + OFF_WWP);
        unsigned short* pbounce = (unsigned short*)(smem + 33280);   // 8 KB
        const int idx   = bid - 97;
        const int h2grp = idx & 31;           // 32-col group of h2
        const int hpb   = (idx >> 5) * 4 + w; // wave's h'-row block (0..31)
        const int h2c0  = h2grp * 32;

        // coalesced stage: W1[:, h2c0..h2c0+32) -> lw1t[col][row] bf16
        for (int i = 0; i < 64; i++) {
            int f = i * 256 + t;
            int row = f >> 5, col = f & 31;
            lw1t[col * 520 + row] = f2bf(W1[(size_t)row * HH + h2c0 + col]);
        }
        __syncthreads();

        f32x4 acc[2][2] = {};
        #pragma unroll 4
        for (int ds = 0; ds < 16; ds++) {
            bf16x8 a[2];
            #pragma unroll
            for (int mt = 0; mt < 2; mt++) {
                const float* w2r = W2 + (size_t)(hpb * 32 + mt * 16 + l15) * DD + ds * 32 + q * 8;
                float4 va = *(const float4*)w2r;
                float4 vb = *(const float4*)(w2r + 4);
                unsigned short tmp[8] = { f2bf(va.x), f2bf(va.y), f2bf(va.z), f2bf(va.w),
                                          f2bf(vb.x), f2bf(vb.y), f2bf(vb.z), f2bf(vb.w) };
                a[mt] = *(bf16x8*)tmp;
            }
            bf16x8 bb0 = *(const bf16x8*)(lw1t + l15 * 520 + ds * 32 + q * 8);
            bf16x8 bb1 = *(const bf16x8*)(lw1t + (16 + l15) * 520 + ds * 32 + q * 8);
            acc[0][0] = __builtin_amdgcn_mfma_f32_16x16x32_bf16(a[0], bb0, acc[0][0], 0, 0, 0);
            acc[0][1] = __builtin_amdgcn_mfma_f32_16x16x32_bf16(a[0], bb1, acc[0][1], 0, 0, 0);
            acc[1][0] = __builtin_amdgcn_mfma_f32_16x16x32_bf16(a[1], bb0, acc[1][0], 0, 0, 0);
            acc[1][1] = __builtin_amdgcn_mfma_f32_16x16x32_bf16(a[1], bb1, acc[1][1], 0, 0, 0);
        }
        unsigned short* pb = pbounce + w * 1024;
        #pragma unroll
        for (int mt = 0; mt < 2; mt++)
            #pragma unroll
            for (int nt = 0; nt < 2; nt++) {
                int lane8 = (mt * 2 + (q >> 1)) * 16 + l15;
                #pragma unroll
                for (int r = 0; r < 4; r++)
                    pb[(nt * 64 + lane8) * 8 + (q & 1) * 4 + r] = f2bf(acc[mt][nt][r]);
            }
        uint4 f0 = *(uint4*)(pb + (0 * 64 + lane) * 8);
        uint4 f1 = *(uint4*)(pb + (1 * 64 + lane) * 8);
        int h2b0 = h2grp * 2;
        *(uint4*)(WWp + ((size_t)(h2b0 + 0) * 32 + hpb) * 512 + lane * 8) = f0;
        *(uint4*)(WWp + ((size_t)(h2b0 + 1) * 32 + hpb) * 512 + lane * 8) = f1;
        return;
    }

    {
        // ---------------- yw1: yW1[b][h2] = sum_d bf16(y) . W1bf ----------
        float* yW1 = ws + OFF_YW1;
        const int h2grp = bid - 353;   // 0..31
        const int h2c0  = h2grp * 32;

        for (int i = 0; i < 64; i++) {
            int f = i * 256 + t;
            int row = f >> 5, col = f & 31;
            lw1t[col * 520 + row] = f2bf(W1[(size_t)row * HH + h2c0 + col]);
        }
        __syncthreads();

        f32x4 acc[2][2] = {};
        #pragma unroll 4
        for (int ds = 0; ds < 16; ds++) {
            bf16x8 a[2];
            #pragma unroll
            for (int mt = 0; mt < 2; mt++) {
                const float* yr = y_init + (size_t)(w * 32 + mt * 16 + l15) * DD + ds * 32 + q * 8;
                float4 va = *(const float4*)yr;
                float4 vb = *(const float4*)(yr + 4);
                unsigned short tmp[8] = { f2bf(va.x), f2bf(va.y), f2bf(va.z), f2bf(va.w),
                                          f2bf(vb.x), f2bf(vb.y), f2bf(vb.z), f2bf(vb.w) };
                a[mt] = *(bf16x8*)tmp;
            }
            bf16x8 bb0 = *(const bf16x8*)(lw1t + l15 * 520 + ds * 32 + q * 8);
            bf16x8 bb1 = *(const bf16x8*)(lw1t + (16 + l15) * 520 + ds * 32 + q * 8);
            acc[0][0] = __builtin_amdgcn_mfma_f32_16x16x32_bf16(a[0], bb0, acc[0][0], 0, 0, 0);
            acc[0][1] = __builtin_amdgcn_mfma_f32_16x16x32_bf16(a[0], bb1, acc[0][1], 0, 0, 0);
            acc[1][0] = __builtin_amdgcn_mfma_f32_16x16x32_bf16(a[1], bb0, acc[1][0], 0, 0, 0);
            acc[1][1] = __builtin_amdgcn_mfma_f32_16x16x32_bf16(a[1], bb1, acc[1][1], 0, 0, 0);
        }
        #pragma unroll
        for (int mt = 0; mt < 2; mt++)
            #pragma unroll
            for (int nt = 0; nt < 2; nt++)
                #pragma unroll
                for (int r = 0; r < 4; r++) {
                    int b  = w * 32 + mt * 16 + q * 4 + r;
                    int h2 = h2c0 + nt * 16 + l15;
                    yW1[(size_t)b * HH + h2] = acc[mt][nt][r];
                }
    }
}

// ---------------------------------------------------------------------------
// K1_0 (first iteration only). Grid 1024 1-D, XCD-swizzled (b = bid&127).
// ---------------------------------------------------------------------------
__global__ __launch_bounds__(256) void k1_kernel(
        const float* __restrict__ B_init,        // [B][512 d][32 n] fp32
        const unsigned short* __restrict__ W1p,  // frag-packed
        const float* __restrict__ b1,            // [1024]
        const float* __restrict__ ws,
        unsigned short* __restrict__ Ptp)        // [B][32 hs][2 mt][64][8] bf16
{
    __shared__ __align__(16) char smem[40960];
    unsigned short* smA  = (unsigned short*)smem;           // A [32 n][512 d] swz
    unsigned short* t_sb = (unsigned short*)smem;           // [128][72] (overlays A)
    unsigned short* g_sb = (unsigned short*)(smem + 32768); // [128][32]

    const int t    = threadIdx.x;
    const int lane = t & 63;
    const int w    = t >> 6;
    const int q    = lane >> 4;
    const int l15  = lane & 15;
    const int bid  = blockIdx.x;
    const int b    = bid & 127;        // XCD affinity: bid%8 = b%8
    const int hblk = bid >> 7;
    const int hw   = hblk * 128 + w * 32;

    // stage: B_init[b] [512 d][32 n] fp32 -> smA bf16 [n][d] swizzled
    {
        const float* Bi = B_init + (size_t)b * DD * NB;
        #pragma unroll 8
        for (int i = 0; i < 64; i++) {
            int f = i * 256 + t;       // 0..16383
            int d = f >> 5, n = f & 31;
            *(unsigned short*)(smem + (((n << 10) + (d << 1)) ^ ((n & 7) << 4)))
                = f2bf(Bi[f]);
        }
    }
    __syncthreads();

    // Phase A: G = A W1^T, M=32(n) x N=32(h/wave) x K=512
    f32x4 acc[2][2] = {};
    const unsigned short* W1b = W1p + (size_t)(hw >> 4) * 8192;
    #pragma unroll 4
    for (int d0 = 0; d0 < DD; d0 += 32) {
        int c16 = (d0 >> 3) + q;
        int ds  = d0 >> 5;
        bf16x8 a0  = *(const bf16x8*)aS(smA, l15, c16);
        bf16x8 a1  = *(const bf16x8*)aS(smA, 16 + l15, c16);
        bf16x8 bb0 = *(const bf16x8*)(W1b + ds * 512 + lane * 8);
        bf16x8 bb1 = *(const bf16x8*)(W1b + 8192 + ds * 512 + lane * 8);
        acc[0][0] = __builtin_amdgcn_mfma_f32_16x16x32_bf16(a0, bb0, acc[0][0], 0, 0, 0);
        acc[0][1] = __builtin_amdgcn_mfma_f32_16x16x32_bf16(a0, bb1, acc[0][1], 0, 0, 0);
        acc[1][0] = __builtin_amdgcn_mfma_f32_16x16x32_bf16(a1, bb0, acc[1][0], 0, 0, 0);
        acc[1][1] = __builtin_amdgcn_mfma_f32_16x16x32_bf16(a1, bb1, acc[1][1], 0, 0, 0);
    }
    #pragma unroll
    for (int mt = 0; mt < 2; mt++)
        #pragma unroll
        for (int nt = 0; nt < 2; nt++) {
            int hl = w * 32 + nt * 16 + l15;
            store4bf(&g_sb[hl * 32 + mt * 16 + q * 4],
                     acc[mt][nt][0], acc[mt][nt][1], acc[mt][nt][2], acc[mt][nt][3]);
        }
    __syncthreads();   // all smA reads complete -> t_sb may overlay

    // Z = Phi_f^T G
    f32x4 zacc[4][2] = {};
    const unsigned short* PF = (const unsigned short*)(ws + OFF_PHIF_BF);
    bf16x8 gb[2];
    #pragma unroll
    for (int nt = 0; nt < 2; nt++)
        gb[nt] = *(const bf16x8*)(&g_sb[(w * 32 + nt * 16 + l15) * 32 + q * 8]);
    #pragma unroll
    for (int mt = 0; mt < 4; mt++) {
        bf16x8 af = *(const bf16x8*)(PF + (mt * 16 + l15) * 32 + q * 8);
        zacc[mt][0] = __builtin_amdgcn_mfma_f32_16x16x32_bf16(af, gb[0], zacc[mt][0], 0, 0, 0);
        zacc[mt][1] = __builtin_amdgcn_mfma_f32_16x16x32_bf16(af, gb[1], zacc[mt][1], 0, 0, 0);
    }

    const float* TTp = ws + OFF_TTRUE;
    float b1v[2] = { b1[hw + l15], b1[hw + 16 + l15] };
    #pragma unroll
    for (int mt = 0; mt < 4; mt++) {
        float4 ttv = *(const float4*)(TTp + mt * 16 + q * 4);
        #pragma unroll
        for (int nt = 0; nt < 2; nt++) {
            int hl = w * 32 + nt * 16 + l15;
            float v0 = tanh_fast(zacc[mt][nt][0] + ttv.x * b1v[nt]);
            float v1 = tanh_fast(zacc[mt][nt][1] + ttv.y * b1v[nt]);
            float v2 = tanh_fast(zacc[mt][nt][2] + ttv.z * b1v[nt]);
            float v3 = tanh_fast(zacc[mt][nt][3] + ttv.w * b1v[nt]);
            store4bf(&t_sb[hl * 72 + mt * 16 + q * 4], v0, v1, v2, v3);
        }
    }
    __syncthreads();

    // P = Q^T T
    f32x4 pacc[2][2] = {};
    const unsigned short* QT = (const unsigned short*)(ws + OFF_QT_BF);
    #pragma unroll
    for (int ks = 0; ks < 2; ks++) {
        bf16x8 bt[2];
        #pragma unroll
        for (int nt = 0; nt < 2; nt++)
            bt[nt] = *(const bf16x8*)(&t_sb[(w * 32 + nt * 16 + l15) * 72 + ks * 32 + q * 8]);
        #pragma unroll
        for (int jt = 0; jt < 2; jt++) {
            bf16x8 aq = *(const bf16x8*)(QT + (jt * 16 + l15) * 64 + ks * 32 + q * 8);
            pacc[jt][0] = __builtin_amdgcn_mfma_f32_16x16x32_bf16(aq, bt[0], pacc[jt][0], 0, 0, 0);
            pacc[jt][1] = __builtin_amdgcn_mfma_f32_16x16x32_bf16(aq, bt[1], pacc[jt][1], 0, 0, 0);
        }
    }

    // pack P -> Ptp via wave-private bounce (g_sb region dead after Z)
    {
        unsigned short* pb = g_sb + w * 1024;
        #pragma unroll
        for (int jt = 0; jt < 2; jt++)
            #pragma unroll
            for (int nt = 0; nt < 2; nt++) {
                int grp = (nt * 2 + (l15 >> 3)) & 3;
                #pragma unroll
                for (int r = 0; r < 4; r++) {
                    int lane8 = grp * 16 + q * 4 + r;
                    pb[(jt * 64 + lane8) * 8 + (l15 & 7)] = f2bf(pacc[jt][nt][r]);
                }
            }
        int hs = hblk * 4 + w;
        uint4 f0 = *(uint4*)(pb + (0 * 64 + lane) * 8);
        uint4 f1 = *(uint4*)(pb + (1 * 64 + lane) * 8);
        *(uint4*)(Ptp + (((size_t)(b * 32 + hs) * 2 + 0) * 64 + lane) * 8) = f0;
        *(uint4*)(Ptp + (((size_t)(b * 32 + hs) * 2 + 1) * 64 + lane) * 8) = f1;
    }
}

// ---------------------------------------------------------------------------
// KF (iterations 1..9): G' = P.WW + u (x) yW1, then Z/tanh/P.
// v4: grid 2048 (b = bid&127, hb4 = bid>>7 in 0..15), 16 h2 per wave,
// A staged in double-buffered 8KB chunks -> LDS 16KB total -> 8 blocks/CU
// = 8 waves/SIMD (2x R16's v3: the latency-hiding the WW stream needs).
// launch_bounds(256,8) caps VGPR at 64 (per-wave state is slim: acc[2],
// zacc[4], pacc[2]). P-pack spans wave PAIRS (each wave holds half an hs):
// parity wp writes disjoint lane8 groups {2wp,2wp+1} into a shared 4KB
// bounce (overlays dead g region, barrier-protected). MFMA s-order and all
// f2bf identical -> bitwise-same numerics.
// ---------------------------------------------------------------------------
__global__ __launch_bounds__(256, 8) void kf_kernel(
        const unsigned short* __restrict__ Ptin,  // [B][32 hs][2 mt][64][8]
        const unsigned short* __restrict__ WWp,   // [64 h2b][32 hs][64][8]
        const float* __restrict__ yW1,            // [B][1024] fp32
        const float* __restrict__ b1,
        const float* __restrict__ ws,
        unsigned short* __restrict__ Ptout)
{
    __shared__ __align__(16) char smem[16384];
    const int t    = threadIdx.x;
    const int lane = t & 63;
    const int w    = t >> 6;       // wave 0..3
    const int q    = lane >> 4;
    const int l15  = lane & 15;
    const int bid  = blockIdx.x;
    const int b    = bid & 127;    // XCD affinity: bid%8 = b%8
    const int hb4  = bid >> 7;     // 0..15
    const int hwv  = hb4 * 64 + w * 16;   // wave's h2 base (16 wide)

    f32x4 acc[2] = {};             // [mt]
    const unsigned short* Ab  = Ptin + (size_t)b * 32768;
    const unsigned short* WWb = WWp + (size_t)(hb4 * 4 + w) * 16384;
    unsigned short* buf0 = (unsigned short*)smem;
    unsigned short* buf1 = (unsigned short*)(smem + 8192);

    {   // stage chunk 0 (8KB = 512 uint4; 2 per thread, coalesced)
        const uint4* src = (const uint4*)Ab;
        uint4* dst = (uint4*)buf0;
        dst[t] = src[t];
        dst[256 + t] = src[256 + t];
    }
    __syncthreads();

    #pragma unroll 1
    for (int c = 0; c < 8; ++c) {
        if (c < 7) {   // prefetch next 8KB chunk into the other buffer
            const uint4* src = (const uint4*)(Ab + (c + 1) * 4096);
            uint4* dst = (uint4*)((c & 1) ? buf0 : buf1);
            dst[t] = src[t];
            dst[256 + t] = src[256 + t];
        }
        const unsigned short* Ac = (c & 1) ? buf1 : buf0;
        #pragma unroll
        for (int sl = 0; sl < 4; ++sl) {
            int s = c * 4 + sl;
            bf16x8 a0 = *(const bf16x8*)(Ac + (sl * 2 + 0) * 512 + lane * 8);
            bf16x8 a1 = *(const bf16x8*)(Ac + (sl * 2 + 1) * 512 + lane * 8);
            bf16x8 bb = *(const bf16x8*)(WWb + s * 512 + lane * 8);
            acc[0] = __builtin_amdgcn_mfma_f32_16x16x32_bf16(a0, bb, acc[0], 0, 0, 0);
            acc[1] = __builtin_amdgcn_mfma_f32_16x16x32_bf16(a1, bb, acc[1], 0, 0, 0);
        }
        __syncthreads();   // prefetch complete + A reads done before overwrite
    }
    // A buffers dead; overlay: g_w (4x1KB at 0..4KB), t_w (4x2304B at 4096..),
    // pb (4KB, overlays g region -- barrier before pack writes).
    unsigned short* g_w = (unsigned short*)(smem + w * 1024);          // [16][32]
    unsigned short* t_w = (unsigned short*)(smem + 4096 + w * 2304);   // [16][72]

    // bias u[j]*yW1[b][h2], write g_w[h2_loc][j]
    const float* U = ws + OFF_U;
    float yw1v = yW1[(size_t)b * HH + hwv + l15];
    #pragma unroll
    for (int mt = 0; mt < 2; mt++) {
        float4 uv = *(const float4*)(U + mt * 16 + q * 4);
        store4bf(&g_w[l15 * 32 + mt * 16 + q * 4],
                 acc[mt][0] + uv.x * yw1v,
                 acc[mt][1] + uv.y * yw1v,
                 acc[mt][2] + uv.z * yw1v,
                 acc[mt][3] + uv.w * yw1v);
    }

    // Z = Phi_f^T G' : M=64(m) x N=16(h2/wave) x K=32(j)
    f32x4 zacc[4] = {};
    const unsigned short* PF = (const unsigned short*)(ws + OFF_PHIF_BF);
    bf16x8 gb = *(const bf16x8*)(&g_w[l15 * 32 + q * 8]);
    #pragma unroll
    for (int mt = 0; mt < 4; mt++) {
        bf16x8 af = *(const bf16x8*)(PF + (mt * 16 + l15) * 32 + q * 8);
        zacc[mt] = __builtin_amdgcn_mfma_f32_16x16x32_bf16(af, gb, zacc[mt], 0, 0, 0);
    }

    const float* TTp = ws + OFF_TTRUE;
    float b1v = b1[hwv + l15];
    #pragma unroll
    for (int mt = 0; mt < 4; mt++) {
        float4 ttv = *(const float4*)(TTp + mt * 16 + q * 4);
        float v0 = tanh_fast(zacc[mt][0] + ttv.x * b1v);
        float v1 = tanh_fast(zacc[mt][1] + ttv.y * b1v);
        float v2 = tanh_fast(zacc[mt][2] + ttv.z * b1v);
        float v3 = tanh_fast(zacc[mt][3] + ttv.w * b1v);
        store4bf(&t_w[l15 * 72 + mt * 16 + q * 4], v0, v1, v2, v3);
    }

    // P = Q^T T : M=32(j) x N=16(h2/wave) x K=64(m)
    f32x4 pacc[2] = {};
    const unsigned short* QT = (const unsigned short*)(ws + OFF_QT_BF);
    #pragma unroll
    for (int ks = 0; ks < 2; ks++) {
        bf16x8 bt = *(const bf16x8*)(&t_w[l15 * 72 + ks * 32 + q * 8]);
        #pragma unroll
        for (int jt = 0; jt < 2; jt++) {
            bf16x8 aq = *(const bf16x8*)(QT + (jt * 16 + l15) * 64 + ks * 32 + q * 8);
            pacc[jt] = __builtin_amdgcn_mfma_f32_16x16x32_bf16(aq, bt, pacc[jt], 0, 0, 0);
        }
    }

    // pack P -> Ptout: wave pair (hs_loc = w>>1) shares one hs fragment set.
    // Wave parity wp = w&1 covers h2 columns [wp*16, wp*16+16) of the hs ->
    // writes disjoint lane8 groups {2wp, 2wp+1}. pb overlays g region (dead
    // after Z's gb load) -- barrier protects cross-wave reuse.
    __syncthreads();
    {
        unsigned short* pbb = (unsigned short*)smem;   // [2 hs][2 jt][64][8] = 4KB
        const int hs_loc = w >> 1, wp = w & 1;
        unsigned short* pb_hs = pbb + hs_loc * 1024;   // 1024 shorts per jt pair? no:
        // per hs: [2 jt][64 lane8][8 e] = 1024 shorts... (2*64*8 = 1024) -> 2KB
        // offset per hs = 1024 shorts; per jt = 512 shorts.
        #pragma unroll
        for (int jt = 0; jt < 2; jt++) {
            int grp = wp * 2 + (l15 >> 3);
            #pragma unroll
            for (int r = 0; r < 4; r++) {
                int lane8 = grp * 16 + q * 4 + r;
                pb_hs[jt * 512 + lane8 * 8 + (l15 & 7)] = f2bf(pacc[jt][r]);
            }
        }
        __syncthreads();
        // readback: thread t -> fragment i = t>>6 (hs_loc = i>>1, jt = i&1)
        int i = t >> 6;
        uint4 fv = *(uint4*)(pbb + i * 512 + lane * 8);
        int hs = hb4 * 2 + (i >> 1), jt = i & 1;
        *(uint4*)(Ptout + (((size_t)(b * 32 + hs) * 2 + jt) * 64 + lane) * 8) = fv;
    }
}

// ---------------------------------------------------------------------------
// K2F (final): Bn_val = P.W2 + y u (fp32); writes out1 directly and
// out0 = sum_n Bn_val*Phi_out. Grid 1024 1-D, XCD-swizzled (b = bid&127).
// ---------------------------------------------------------------------------
__global__ __launch_bounds__(256) void k2f_kernel(
        const unsigned short* __restrict__ Ptp,  // [B][32 hs][2 mt][64][8] bf16
        const unsigned short* __restrict__ W2p,  // frag-packed
        const float* __restrict__ y_init,        // [B][512]
        const float* __restrict__ ws,
        float* __restrict__ out)
{
    __shared__ __align__(16) float ls[4 * 544];
    __shared__ float phiout_s[NB * TT];

    const int t    = threadIdx.x;
    const int lane = t & 63;
    const int w    = t >> 6;
    const int q    = lane >> 4;
    const int l15  = lane & 15;
    const int bid  = blockIdx.x;
    const int b    = bid & 127;        // XCD affinity
    const int dblk = bid >> 7;         // 0..7
    const int dw   = dblk * 64 + w * 16;

    for (int f = t; f < NB * TT; f += 256) phiout_s[f] = ws[OFF_PHIOUT + f];

    f32x4 acc[2] = {};
    const unsigned short* Ab  = Ptp + (size_t)b * 32768;
    const unsigned short* W2b = W2p + (size_t)(dblk * 4 + w) * 16384;
    #pragma unroll 4
    for (int s = 0; s < 32; s++) {
        bf16x8 a0 = *(const bf16x8*)(Ab + (s * 2 + 0) * 512 + lane * 8);
        bf16x8 a1 = *(const bf16x8*)(Ab + (s * 2 + 1) * 512 + lane * 8);
        bf16x8 bb = *(const bf16x8*)(W2b + s * 512 + lane * 8);
        acc[0] = __builtin_amdgcn_mfma_f32_16x16x32_bf16(a0, bb, acc[0], 0, 0, 0);
        acc[1] = __builtin_amdgcn_mfma_f32_16x16x32_bf16(a1, bb, acc[1], 0, 0, 0);
    }

    const float* U = ws + OFF_U;
    float yv = y_init[(size_t)b * DD + dw + l15];
    #pragma unroll
    for (int mt = 0; mt < 2; mt++) {
        float4 uv = *(const float4*)(U + mt * 16 + q * 4);
        #pragma unroll
        for (int r = 0; r < 4; r++) {
            int j = mt * 16 + q * 4 + r;
            float uvr = (r == 0) ? uv.x : (r == 1) ? uv.y : (r == 2) ? uv.z : uv.w;
            ls[w * 544 + j * 17 + l15] = acc[mt][r] + yv * uvr;
        }
    }
    __syncthreads();

    // out1 = Bn copy (coalesced)
    float* out1 = out + (size_t)TT * BB * DD;
    #pragma unroll
    for (int it = 0; it < 8; it++) {
        int f = it * 64 + lane;
        int d_l = f >> 5, j2 = f & 31;
        out1[((size_t)b * DD + dw + d_l) * NB + j2] = ls[w * 544 + j2 * 17 + d_l];
    }

    // out0[t16, b, d] = sum_n val[d][n] * phiout[n][t16]   (64 d x 16 t per block)
    #pragma unroll
    for (int i = 0; i < 4; i++) {
        int idx = i * 256 + t;
        int t16 = idx >> 6, dl = idx & 63;
        float s = 0.f;
        #pragma unroll
        for (int n = 0; n < NB; n++)
            s += ls[(dl >> 4) * 544 + n * 17 + (dl & 15)] * phiout_s[n * TT + t16];
        out[(size_t)t16 * (BB * DD) + (size_t)b * DD + dblk * 64 + dl] = s;
    }
}

// ---------------------------------------------------------------------------
extern "C" void kernel_launch(void* const* d_in, const int* in_sizes, int n_in,
                              void* d_out, int out_size, void* d_ws, size_t ws_size,
                              hipStream_t stream) {
    const float* t_span = (const float*)d_in[0];
    const float* y_init = (const float*)d_in[1];
    const float* B_init = (const float*)d_in[2];
    const float* W1     = (const float*)d_in[3];
    const float* b1     = (const float*)d_in[4];
    const float* W2     = (const float*)d_in[5];
    float* ws  = (float*)d_ws;
    float* out = (float*)d_out;

    unsigned short* W1p  = (unsigned short*)(ws + OFF_W1P);
    unsigned short* W2p  = (unsigned short*)(ws + OFF_W2P);
    unsigned short* WWp  = (unsigned short*)(ws + OFF_WWP);
    float*          yW1  = ws + OFF_YW1;
    unsigned short* PtpA = (unsigned short*)(ws + OFF_PTPA);
    unsigned short* PtpB = (unsigned short*)(ws + OFF_PTP0);

    // ONE prologue dispatch: setup + pack_w1 + pack_w2 + pack_ww + yw1
    prologue_kernel<<<dim3(385), 256, 0, stream>>>(t_span, W1, W2, y_init, ws);

    k1_kernel<<<dim3(1024), 256, 0, stream>>>(B_init, W1p, b1, ws, PtpA);

    unsigned short* pin  = PtpA;
    unsigned short* pout = PtpB;
    for (int it = 1; it < ITERS; it++) {
        kf_kernel<<<dim3(2048), 256, 0, stream>>>(pin, WWp, yW1, b1, ws, pout);
        unsigned short* tmp = pin; pin = pout; pout = tmp;
    }
    // 9 kf's -> final P in pin
    k2f_kernel<<<dim3(1024), 256, 0, stream>>>(pin, W2p, y_init, ws, out);
}

// Round 18
// 320.238 us; speedup vs baseline: 1.0599x; 1.0599x over previous
//
#include <hip/hip_runtime.h>
#include <hip/hip_bf16.h>
#include <math.h>

// Problem constants (fixed by setup_inputs)
#define BB 128
#define DD 512
#define HH 1024
#define NB 32     // num_coeff_per_dim
#define MM 63     // 2N-1 simpson points
#define TT 16
#define ITERS 10

// ws layout (float units)
#define OFF_U       0        // 32 fp32
#define OFF_TTRUE   64       // 64 fp32 (tt[63]=0)
#define OFF_PHIOUT  128      // 512 fp32
#define OFF_PHIF_BF 1024     // bf16 [64 m][32 n]  (row 63 = 0)   = 1024 floats
#define OFF_QT_BF   2048     // bf16 [32 j][64 m]  (col 63 = 0)   = 1024 floats
#define HDRF        4096
#define OFF_PTPA    HDRF                     // bf16 frag-packed [B][32 hs][2 mt][64][8] = 2097152 f
#define OFF_PTP0    (OFF_PTPA + 2097152)     // bf16 frag-packed ping-pong buffer       = 2097152 f
#define OFF_W1P     (OFF_PTP0 + 2097152)     // bf16 frag-packed [64 hb][16 ds][64][8] = 262144 f
#define OFF_W2P     (OFF_W1P + 262144)       // bf16 frag-packed [32 db][32 hs][64][8] = 262144 f
#define OFF_WWP     (OFF_W2P + 262144)       // bf16 frag-packed [64 h2b][32 hs][64][8] = 524288 f
#define OFF_YW1     (OFF_WWP + 524288)       // fp32 [128 b][1024 h2] = 131072 f
// end = 5378048 floats = 21.5 MB

typedef __attribute__((ext_vector_type(8))) short bf16x8;
typedef __attribute__((ext_vector_type(4))) float f32x4;

static __device__ __forceinline__ unsigned short f2bf(float f) {
    unsigned int x = __builtin_bit_cast(unsigned int, f);
    unsigned int r = x + 0x7FFFu + ((x >> 16) & 1u);   // RNE
    return (unsigned short)(r >> 16);
}

static __device__ __forceinline__ void store4bf(unsigned short* p,
                                                float v0, float v1, float v2, float v3) {
    unsigned int lo = (unsigned int)f2bf(v0) | ((unsigned int)f2bf(v1) << 16);
    unsigned int hi = (unsigned int)f2bf(v2) | ((unsigned int)f2bf(v3) << 16);
    uint2 u; u.x = lo; u.y = hi;
    *(uint2*)p = u;   // 8B-aligned by construction
}

static __device__ __forceinline__ float tanh_fast(float x) {
    float e = exp2f(x * 2.88539008177793f);   // 2*log2(e)
    return 1.0f - 2.0f / (e + 1.0f);
}

// XOR-swizzled LDS A-tile addressing: tile [32 r][512 c] bf16, linear 32KB,
// byte = (r*1024 + c*2) ^ ((r&7)<<4). Bijective per row, 16B-aligned b128.
static __device__ __forceinline__ unsigned short* aS(unsigned short* smA, int r, int c16) {
    return (unsigned short*)((char*)smA + (((r << 10) + (c16 << 4)) ^ ((r & 7) << 4)));
}

// ---------------------------------------------------------------------------
// PROLOGUE (single dispatch, blocks partitioned by role):
//   bid 0        : setup -- closed-form DCT-I Phi_inv (no GJ)
//   bid 1..64    : pack_w1   (hb = bid-1)
//   bid 65..96   : pack_w2   (db = bid-65)
//   bid 97..352  : pack_ww   (idx: h2grp = idx&31, hpb = (idx>>5)*4+w)
//   bid 353..384 : yw1       (h2grp = bid-353, waves = b-tiles)
// ---------------------------------------------------------------------------
__global__ __launch_bounds__(256) void prologue_kernel(
        const float* __restrict__ t_span, const float* __restrict__ W1,
        const float* __restrict__ W2, const float* __restrict__ y_init,
        float* __restrict__ ws) {
    __shared__ __align__(16) char smem[66560];
    const int bid  = blockIdx.x;
    const int t    = threadIdx.x;
    const int lane = t & 63;
    const int w    = t >> 6;
    const int q    = lane >> 4;
    const int l15  = lane & 15;

    if (bid == 0) {
        // ---------------- setup ----------------
        double* tsim    = (double*)(smem + 0);       // 63
        double* ttrue_d = (double*)(smem + 512);     // 63
        double* wid     = (double*)(smem + 1024);    // 31
        double* phid    = (double*)(smem + 1280);    // 32*63
        double* pinv    = (double*)(smem + 17408);   // 32*32 closed-form Phi_inv
        double* Rl      = (double*)(smem + 34048);   // 63*32
        double* Qd      = (double*)(smem + 50176);   // 63*32

        const double PI = 3.14159265358979323846;
        const double t0 = (double)t_span[0];
        const double t1 = (double)t_span[TT - 1];

        if (t < MM) {
            double v;
            if ((t & 1) == 0) {
                int j = t >> 1;
                v = -cos(PI * (double)j / (double)(NB - 1));
            } else {
                int i = t >> 1;
                double a = -cos(PI * (double)i / (double)(NB - 1));
                double b = -cos(PI * (double)(i + 1) / (double)(NB - 1));
                v = 0.5 * (a + b);
            }
            tsim[t] = v;
            ttrue_d[t] = t0 + 0.5 * (t1 - t0) * (v + 1.0);
        }
        __syncthreads();
        if (t < 31) wid[t] = (ttrue_d[2 * t + 2] - ttrue_d[2 * t]) / 6.0;
        if (t < MM) ws[OFF_TTRUE + t] = (float)ttrue_d[t];
        if (t == 63) ws[OFF_TTRUE + 63] = 0.0f;

        if (t < MM) {
            double x = tsim[t];
            double r0 = 1.0, r1 = x;
            phid[0 * MM + t] = r0;
            phid[1 * MM + t] = r1;
            for (int n = 2; n < NB; n++) {
                double r2 = 2.0 * x * r1 - r0;
                phid[n * MM + t] = r2;
                r0 = r1; r1 = r2;
            }
        }

        // closed-form Phi_inv (independent of phid)
        for (int f = t; f < NB * NB; f += 256) {
            int i = f >> 5, j = f & 31;
            double ci = (i == 0 || i == NB - 1) ? 2.0 : 1.0;
            double cj = (j == 0 || j == NB - 1) ? 2.0 : 1.0;
            double v = 2.0 * cos(PI * (double)(i * j) / (double)(NB - 1))
                       / ((double)(NB - 1) * ci * cj);
            pinv[f] = (j & 1) ? -v : v;
        }
        __syncthreads();

        {   // phif_bf [m 64][n 32], row 63 = 0
            unsigned short* pf = (unsigned short*)(ws + OFF_PHIF_BF);
            for (int f = t; f < 64 * 32; f += 256) {
                int m = f >> 5, n = f & 31;
                pf[f] = f2bf(m < MM ? (float)phid[n * MM + m] : 0.0f);
            }
        }

        if (t < MM) {
            double acc = 0.0;
            Rl[t * NB + 0] = 0.0;
            for (int i = 1; i < NB; i++) {
                int ip = i - 1;
                double wv = 0.0;
                if (t == 2 * ip)     wv += wid[ip];
                if (t == 2 * ip + 1) wv += 4.0 * wid[ip];
                if (t == 2 * ip + 2) wv += wid[ip];
                acc += wv;
                Rl[t * NB + i] = acc;
            }
        }
        __syncthreads();

        for (int f = t; f < MM * NB; f += 256) {
            int m = f >> 5, j = f & 31;
            double s = 0.0;
            for (int i = 0; i < NB; i++) s += Rl[m * NB + i] * pinv[i * 32 + j];
            Qd[f] = s;
        }
        __syncthreads();

        {   // qt_bf [j 32][m 64], col 63 = 0
            unsigned short* qt = (unsigned short*)(ws + OFF_QT_BF);
            for (int f = t; f < 32 * 64; f += 256) {
                int j = f >> 6, m = f & 63;
                qt[f] = f2bf(m < MM ? (float)Qd[m * NB + j] : 0.0f);
            }
        }
        if (t < NB) {
            double s = 0.0;
            for (int i = 0; i < NB; i++) s += pinv[i * 32 + t];
            ws[OFF_U + t] = (float)s;
        }
        if (t < TT) {
            double x = -1.0 + 2.0 * ((double)t_span[t] - t0) / (t1 - t0);
            double r0 = 1.0, r1 = x;
            ws[OFF_PHIOUT + 0 * TT + t] = 1.0f;
            ws[OFF_PHIOUT + 1 * TT + t] = (float)x;
            for (int n = 2; n < NB; n++) {
                double r2 = 2.0 * x * r1 - r0;
                ws[OFF_PHIOUT + n * TT + t] = (float)r2;
                r0 = r1; r1 = r2;
            }
        }
        return;
    }

    if (bid <= 64) {
        // ---------------- pack_w1: hb = bid-1 ----------------
        unsigned short* W1p = (unsigned short*)(ws + OFF_W1P);
        const int hb = bid - 1;
        #pragma unroll
        for (int i = 0; i < 4; i++) {
            int f = i * 256 + t;
            int ds = f >> 6, ln = f & 63;
            int qq = ln >> 4, ll = ln & 15;
            unsigned short tmp[8];
            #pragma unroll
            for (int e = 0; e < 8; e++)
                tmp[e] = f2bf(W1[(size_t)(ds * 32 + qq * 8 + e) * HH + hb * 16 + ll]);
            *(uint4*)(W1p + ((size_t)(hb * 16 + ds) * 64 + ln) * 8) = *(uint4*)tmp;
        }
        return;
    }

    if (bid <= 96) {
        // ---------------- pack_w2: db = bid-65 ----------------
        unsigned short* W2p = (unsigned short*)(ws + OFF_W2P);
        const int db = bid - 65;
        #pragma unroll
        for (int i = 0; i < 8; i++) {
            int f = i * 256 + t;
            int hs = f >> 6, ln = f & 63;
            int qq = ln >> 4, ll = ln & 15;
            unsigned short tmp[8];
            #pragma unroll
            for (int e = 0; e < 8; e++)
                tmp[e] = f2bf(W2[(size_t)(hs * 32 + qq * 8 + e) * DD + db * 16 + ll]);
            *(uint4*)(W2p + ((size_t)(db * 32 + hs) * 64 + ln) * 8) = *(uint4*)tmp;
        }
        return;
    }

    // lw1t = bf16 TRANSPOSED W1 slice: [32 col][520 row-stride] = 33280 B.
    unsigned short* lw1t = (unsigned short*)smem;

    if (bid <= 352) {
        // ---------------- pack_ww: WW = bf16(W2bf . W1bf), frag-packed ----
        unsigned short* WWp = (unsigned short*)(ws + OFF_WWP);
        unsigned short* pbounce = (unsigned short*)(smem + 33280);   // 8 KB
        const int idx   = bid - 97;
        const int h2grp = idx & 31;           // 32-col group of h2
        const int hpb   = (idx >> 5) * 4 + w; // wave's h'-row block (0..31)
        const int h2c0  = h2grp * 32;

        // coalesced stage: W1[:, h2c0..h2c0+32) -> lw1t[col][row] bf16
        for (int i = 0; i < 64; i++) {
            int f = i * 256 + t;
            int row = f >> 5, col = f & 31;
            lw1t[col * 520 + row] = f2bf(W1[(size_t)row * HH + h2c0 + col]);
        }
        __syncthreads();

        f32x4 acc[2][2] = {};
        #pragma unroll 4
        for (int ds = 0; ds < 16; ds++) {
            bf16x8 a[2];
            #pragma unroll
            for (int mt = 0; mt < 2; mt++) {
                const float* w2r = W2 + (size_t)(hpb * 32 + mt * 16 + l15) * DD + ds * 32 + q * 8;
                float4 va = *(const float4*)w2r;
                float4 vb = *(const float4*)(w2r + 4);
                unsigned short tmp[8] = { f2bf(va.x), f2bf(va.y), f2bf(va.z), f2bf(va.w),
                                          f2bf(vb.x), f2bf(vb.y), f2bf(vb.z), f2bf(vb.w) };
                a[mt] = *(bf16x8*)tmp;
            }
            bf16x8 bb0 = *(const bf16x8*)(lw1t + l15 * 520 + ds * 32 + q * 8);
            bf16x8 bb1 = *(const bf16x8*)(lw1t + (16 + l15) * 520 + ds * 32 + q * 8);
            acc[0][0] = __builtin_amdgcn_mfma_f32_16x16x32_bf16(a[0], bb0, acc[0][0], 0, 0, 0);
            acc[0][1] = __builtin_amdgcn_mfma_f32_16x16x32_bf16(a[0], bb1, acc[0][1], 0, 0, 0);
            acc[1][0] = __builtin_amdgcn_mfma_f32_16x16x32_bf16(a[1], bb0, acc[1][0], 0, 0, 0);
            acc[1][1] = __builtin_amdgcn_mfma_f32_16x16x32_bf16(a[1], bb1, acc[1][1], 0, 0, 0);
        }
        unsigned short* pb = pbounce + w * 1024;
        #pragma unroll
        for (int mt = 0; mt < 2; mt++)
            #pragma unroll
            for (int nt = 0; nt < 2; nt++) {
                int lane8 = (mt * 2 + (q >> 1)) * 16 + l15;
                #pragma unroll
                for (int r = 0; r < 4; r++)
                    pb[(nt * 64 + lane8) * 8 + (q & 1) * 4 + r] = f2bf(acc[mt][nt][r]);
            }
        uint4 f0 = *(uint4*)(pb + (0 * 64 + lane) * 8);
        uint4 f1 = *(uint4*)(pb + (1 * 64 + lane) * 8);
        int h2b0 = h2grp * 2;
        *(uint4*)(WWp + ((size_t)(h2b0 + 0) * 32 + hpb) * 512 + lane * 8) = f0;
        *(uint4*)(WWp + ((size_t)(h2b0 + 1) * 32 + hpb) * 512 + lane * 8) = f1;
        return;
    }

    {
        // ---------------- yw1: yW1[b][h2] = sum_d bf16(y) . W1bf ----------
        float* yW1 = ws + OFF_YW1;
        const int h2grp = bid - 353;   // 0..31
        const int h2c0  = h2grp * 32;

        for (int i = 0; i < 64; i++) {
            int f = i * 256 + t;
            int row = f >> 5, col = f & 31;
            lw1t[col * 520 + row] = f2bf(W1[(size_t)row * HH + h2c0 + col]);
        }
        __syncthreads();

        f32x4 acc[2][2] = {};
        #pragma unroll 4
        for (int ds = 0; ds < 16; ds++) {
            bf16x8 a[2];
            #pragma unroll
            for (int mt = 0; mt < 2; mt++) {
                const float* yr = y_init + (size_t)(w * 32 + mt * 16 + l15) * DD + ds * 32 + q * 8;
                float4 va = *(const float4*)yr;
                float4 vb = *(const float4*)(yr + 4);
                unsigned short tmp[8] = { f2bf(va.x), f2bf(va.y), f2bf(va.z), f2bf(va.w),
                                          f2bf(vb.x), f2bf(vb.y), f2bf(vb.z), f2bf(vb.w) };
                a[mt] = *(bf16x8*)tmp;
            }
            bf16x8 bb0 = *(const bf16x8*)(lw1t + l15 * 520 + ds * 32 + q * 8);
            bf16x8 bb1 = *(const bf16x8*)(lw1t + (16 + l15) * 520 + ds * 32 + q * 8);
            acc[0][0] = __builtin_amdgcn_mfma_f32_16x16x32_bf16(a[0], bb0, acc[0][0], 0, 0, 0);
            acc[0][1] = __builtin_amdgcn_mfma_f32_16x16x32_bf16(a[0], bb1, acc[0][1], 0, 0, 0);
            acc[1][0] = __builtin_amdgcn_mfma_f32_16x16x32_bf16(a[1], bb0, acc[1][0], 0, 0, 0);
            acc[1][1] = __builtin_amdgcn_mfma_f32_16x16x32_bf16(a[1], bb1, acc[1][1], 0, 0, 0);
        }
        #pragma unroll
        for (int mt = 0; mt < 2; mt++)
            #pragma unroll
            for (int nt = 0; nt < 2; nt++)
                #pragma unroll
                for (int r = 0; r < 4; r++) {
                    int b  = w * 32 + mt * 16 + q * 4 + r;
                    int h2 = h2c0 + nt * 16 + l15;
                    yW1[(size_t)b * HH + h2] = acc[mt][nt][r];
                }
    }
}

// ---------------------------------------------------------------------------
// K1_0 (first iteration only). Grid 1024 1-D, XCD-swizzled (b = bid&127).
// ---------------------------------------------------------------------------
__global__ __launch_bounds__(256) void k1_kernel(
        const float* __restrict__ B_init,        // [B][512 d][32 n] fp32
        const unsigned short* __restrict__ W1p,  // frag-packed
        const float* __restrict__ b1,            // [1024]
        const float* __restrict__ ws,
        unsigned short* __restrict__ Ptp)        // [B][32 hs][2 mt][64][8] bf16
{
    __shared__ __align__(16) char smem[40960];
    unsigned short* smA  = (unsigned short*)smem;           // A [32 n][512 d] swz
    unsigned short* t_sb = (unsigned short*)smem;           // [128][72] (overlays A)
    unsigned short* g_sb = (unsigned short*)(smem + 32768); // [128][32]

    const int t    = threadIdx.x;
    const int lane = t & 63;
    const int w    = t >> 6;
    const int q    = lane >> 4;
    const int l15  = lane & 15;
    const int bid  = blockIdx.x;
    const int b    = bid & 127;        // XCD affinity: bid%8 = b%8
    const int hblk = bid >> 7;
    const int hw   = hblk * 128 + w * 32;

    // stage: B_init[b] [512 d][32 n] fp32 -> smA bf16 [n][d] swizzled
    {
        const float* Bi = B_init + (size_t)b * DD * NB;
        #pragma unroll 8
        for (int i = 0; i < 64; i++) {
            int f = i * 256 + t;       // 0..16383
            int d = f >> 5, n = f & 31;
            *(unsigned short*)(smem + (((n << 10) + (d << 1)) ^ ((n & 7) << 4)))
                = f2bf(Bi[f]);
        }
    }
    __syncthreads();

    // Phase A: G = A W1^T, M=32(n) x N=32(h/wave) x K=512
    f32x4 acc[2][2] = {};
    const unsigned short* W1b = W1p + (size_t)(hw >> 4) * 8192;
    #pragma unroll 4
    for (int d0 = 0; d0 < DD; d0 += 32) {
        int c16 = (d0 >> 3) + q;
        int ds  = d0 >> 5;
        bf16x8 a0  = *(const bf16x8*)aS(smA, l15, c16);
        bf16x8 a1  = *(const bf16x8*)aS(smA, 16 + l15, c16);
        bf16x8 bb0 = *(const bf16x8*)(W1b + ds * 512 + lane * 8);
        bf16x8 bb1 = *(const bf16x8*)(W1b + 8192 + ds * 512 + lane * 8);
        acc[0][0] = __builtin_amdgcn_mfma_f32_16x16x32_bf16(a0, bb0, acc[0][0], 0, 0, 0);
        acc[0][1] = __builtin_amdgcn_mfma_f32_16x16x32_bf16(a0, bb1, acc[0][1], 0, 0, 0);
        acc[1][0] = __builtin_amdgcn_mfma_f32_16x16x32_bf16(a1, bb0, acc[1][0], 0, 0, 0);
        acc[1][1] = __builtin_amdgcn_mfma_f32_16x16x32_bf16(a1, bb1, acc[1][1], 0, 0, 0);
    }
    #pragma unroll
    for (int mt = 0; mt < 2; mt++)
        #pragma unroll
        for (int nt = 0; nt < 2; nt++) {
            int hl = w * 32 + nt * 16 + l15;
            store4bf(&g_sb[hl * 32 + mt * 16 + q * 4],
                     acc[mt][nt][0], acc[mt][nt][1], acc[mt][nt][2], acc[mt][nt][3]);
        }
    __syncthreads();   // all smA reads complete -> t_sb may overlay

    // Z = Phi_f^T G
    f32x4 zacc[4][2] = {};
    const unsigned short* PF = (const unsigned short*)(ws + OFF_PHIF_BF);
    bf16x8 gb[2];
    #pragma unroll
    for (int nt = 0; nt < 2; nt++)
        gb[nt] = *(const bf16x8*)(&g_sb[(w * 32 + nt * 16 + l15) * 32 + q * 8]);
    #pragma unroll
    for (int mt = 0; mt < 4; mt++) {
        bf16x8 af = *(const bf16x8*)(PF + (mt * 16 + l15) * 32 + q * 8);
        zacc[mt][0] = __builtin_amdgcn_mfma_f32_16x16x32_bf16(af, gb[0], zacc[mt][0], 0, 0, 0);
        zacc[mt][1] = __builtin_amdgcn_mfma_f32_16x16x32_bf16(af, gb[1], zacc[mt][1], 0, 0, 0);
    }

    const float* TTp = ws + OFF_TTRUE;
    float b1v[2] = { b1[hw + l15], b1[hw + 16 + l15] };
    #pragma unroll
    for (int mt = 0; mt < 4; mt++) {
        float4 ttv = *(const float4*)(TTp + mt * 16 + q * 4);
        #pragma unroll
        for (int nt = 0; nt < 2; nt++) {
            int hl = w * 32 + nt * 16 + l15;
            float v0 = tanh_fast(zacc[mt][nt][0] + ttv.x * b1v[nt]);
            float v1 = tanh_fast(zacc[mt][nt][1] + ttv.y * b1v[nt]);
            float v2 = tanh_fast(zacc[mt][nt][2] + ttv.z * b1v[nt]);
            float v3 = tanh_fast(zacc[mt][nt][3] + ttv.w * b1v[nt]);
            store4bf(&t_sb[hl * 72 + mt * 16 + q * 4], v0, v1, v2, v3);
        }
    }
    __syncthreads();

    // P = Q^T T
    f32x4 pacc[2][2] = {};
    const unsigned short* QT = (const unsigned short*)(ws + OFF_QT_BF);
    #pragma unroll
    for (int ks = 0; ks < 2; ks++) {
        bf16x8 bt[2];
        #pragma unroll
        for (int nt = 0; nt < 2; nt++)
            bt[nt] = *(const bf16x8*)(&t_sb[(w * 32 + nt * 16 + l15) * 72 + ks * 32 + q * 8]);
        #pragma unroll
        for (int jt = 0; jt < 2; jt++) {
            bf16x8 aq = *(const bf16x8*)(QT + (jt * 16 + l15) * 64 + ks * 32 + q * 8);
            pacc[jt][0] = __builtin_amdgcn_mfma_f32_16x16x32_bf16(aq, bt[0], pacc[jt][0], 0, 0, 0);
            pacc[jt][1] = __builtin_amdgcn_mfma_f32_16x16x32_bf16(aq, bt[1], pacc[jt][1], 0, 0, 0);
        }
    }

    // pack P -> Ptp via wave-private bounce (g_sb region dead after Z)
    {
        unsigned short* pb = g_sb + w * 1024;
        #pragma unroll
        for (int jt = 0; jt < 2; jt++)
            #pragma unroll
            for (int nt = 0; nt < 2; nt++) {
                int grp = (nt * 2 + (l15 >> 3)) & 3;
                #pragma unroll
                for (int r = 0; r < 4; r++) {
                    int lane8 = grp * 16 + q * 4 + r;
                    pb[(jt * 64 + lane8) * 8 + (l15 & 7)] = f2bf(pacc[jt][nt][r]);
                }
            }
        int hs = hblk * 4 + w;
        uint4 f0 = *(uint4*)(pb + (0 * 64 + lane) * 8);
        uint4 f1 = *(uint4*)(pb + (1 * 64 + lane) * 8);
        *(uint4*)(Ptp + (((size_t)(b * 32 + hs) * 2 + 0) * 64 + lane) * 8) = f0;
        *(uint4*)(Ptp + (((size_t)(b * 32 + hs) * 2 + 1) * 64 + lane) * 8) = f1;
    }
}

// ---------------------------------------------------------------------------
// KF (iterations 1..9): G' = P.WW + u (x) yW1, then Z/tanh/P.
// v3 (best measured): grid 1024 (b = bid&127, hblk = bid>>7), N=32 h2/wave,
// shared double-buffered A staging in 32KB LDS -> 4 blocks/CU = 4 waves/SIMD.
// (v4's 8 waves/SIMD regressed: doubled A-traffic + halved MFMA-per-barrier.)
// ---------------------------------------------------------------------------
__global__ __launch_bounds__(256) void kf_kernel(
        const unsigned short* __restrict__ Ptin,  // [B][32 hs][2 mt][64][8]
        const unsigned short* __restrict__ WWp,   // [64 h2b][32 hs][64][8]
        const float* __restrict__ yW1,            // [B][1024] fp32
        const float* __restrict__ b1,
        const float* __restrict__ ws,
        unsigned short* __restrict__ Ptout)
{
    __shared__ __align__(16) char smem[32768];
    const int t    = threadIdx.x;
    const int lane = t & 63;
    const int w    = t >> 6;
    const int q    = lane >> 4;
    const int l15  = lane & 15;
    const int bid  = blockIdx.x;
    const int b    = bid & 127;        // XCD affinity: bid%8 = b%8
    const int hblk = bid >> 7;         // 0..7
    const int hw   = hblk * 128 + w * 32;

    f32x4 acc[2][2] = {};
    const unsigned short* Ab  = Ptin + (size_t)b * 32768;
    const unsigned short* WWb = WWp + (size_t)(hw >> 4) * 16384;
    unsigned short* buf0 = (unsigned short*)smem;
    unsigned short* buf1 = (unsigned short*)(smem + 16384);

    {   // stage chunk 0 (16KB, coalesced, shared by all 4 waves)
        const uint4* src = (const uint4*)Ab;
        uint4* dst = (uint4*)buf0;
        #pragma unroll
        for (int i = 0; i < 4; i++) dst[i * 256 + t] = src[i * 256 + t];
    }
    __syncthreads();

    #pragma unroll 1
    for (int c = 0; c < 4; ++c) {
        if (c < 3) {   // prefetch next chunk into the other buffer
            const uint4* src = (const uint4*)(Ab + (c + 1) * 8192);
            uint4* dst = (uint4*)((c & 1) ? buf0 : buf1);
            #pragma unroll
            for (int i = 0; i < 4; i++) dst[i * 256 + t] = src[i * 256 + t];
        }
        const unsigned short* Ac = (c & 1) ? buf1 : buf0;
        #pragma unroll
        for (int sl = 0; sl < 8; ++sl) {
            int s = c * 8 + sl;
            bf16x8 a0  = *(const bf16x8*)(Ac + (sl * 2 + 0) * 512 + lane * 8);
            bf16x8 a1  = *(const bf16x8*)(Ac + (sl * 2 + 1) * 512 + lane * 8);
            bf16x8 bb0 = *(const bf16x8*)(WWb + s * 512 + lane * 8);
            bf16x8 bb1 = *(const bf16x8*)(WWb + 16384 + s * 512 + lane * 8);
            acc[0][0] = __builtin_amdgcn_mfma_f32_16x16x32_bf16(a0, bb0, acc[0][0], 0, 0, 0);
            acc[0][1] = __builtin_amdgcn_mfma_f32_16x16x32_bf16(a0, bb1, acc[0][1], 0, 0, 0);
            acc[1][0] = __builtin_amdgcn_mfma_f32_16x16x32_bf16(a1, bb0, acc[1][0], 0, 0, 0);
            acc[1][1] = __builtin_amdgcn_mfma_f32_16x16x32_bf16(a1, bb1, acc[1][1], 0, 0, 0);
        }
        __syncthreads();   // prefetch complete + A reads done before overwrite
    }
    // A buffers dead; wave-private phase-B scratch overlays them:
    unsigned short* g_w = (unsigned short*)(smem + w * 2048);          // [32][32]
    unsigned short* t_w = (unsigned short*)(smem + 8192 + w * 4608);   // [32][72]
    unsigned short* pb_w = g_w;    // reused after Z consumes g

    // bias u[j]*yW1[b][h2], write g_w[h2_loc][j]
    const float* U = ws + OFF_U;
    float yw[2] = { yW1[(size_t)b * HH + hw + l15],
                    yW1[(size_t)b * HH + hw + 16 + l15] };
    #pragma unroll
    for (int mt = 0; mt < 2; mt++) {
        float4 uv = *(const float4*)(U + mt * 16 + q * 4);
        #pragma unroll
        for (int nt = 0; nt < 2; nt++) {
            int hl = nt * 16 + l15;
            store4bf(&g_w[hl * 32 + mt * 16 + q * 4],
                     acc[mt][nt][0] + uv.x * yw[nt],
                     acc[mt][nt][1] + uv.y * yw[nt],
                     acc[mt][nt][2] + uv.z * yw[nt],
                     acc[mt][nt][3] + uv.w * yw[nt]);
        }
    }

    // Z = Phi_f^T G' : M=64(m) x N=32(h2/wave) x K=32(j)
    f32x4 zacc[4][2] = {};
    const unsigned short* PF = (const unsigned short*)(ws + OFF_PHIF_BF);
    bf16x8 gb[2];
    #pragma unroll
    for (int nt = 0; nt < 2; nt++)
        gb[nt] = *(const bf16x8*)(&g_w[(nt * 16 + l15) * 32 + q * 8]);
    #pragma unroll
    for (int mt = 0; mt < 4; mt++) {
        bf16x8 af = *(const bf16x8*)(PF + (mt * 16 + l15) * 32 + q * 8);
        zacc[mt][0] = __builtin_amdgcn_mfma_f32_16x16x32_bf16(af, gb[0], zacc[mt][0], 0, 0, 0);
        zacc[mt][1] = __builtin_amdgcn_mfma_f32_16x16x32_bf16(af, gb[1], zacc[mt][1], 0, 0, 0);
    }

    const float* TTp = ws + OFF_TTRUE;
    float b1v[2] = { b1[hw + l15], b1[hw + 16 + l15] };
    #pragma unroll
    for (int mt = 0; mt < 4; mt++) {
        float4 ttv = *(const float4*)(TTp + mt * 16 + q * 4);
        #pragma unroll
        for (int nt = 0; nt < 2; nt++) {
            int hl = nt * 16 + l15;
            float v0 = tanh_fast(zacc[mt][nt][0] + ttv.x * b1v[nt]);
            float v1 = tanh_fast(zacc[mt][nt][1] + ttv.y * b1v[nt]);
            float v2 = tanh_fast(zacc[mt][nt][2] + ttv.z * b1v[nt]);
            float v3 = tanh_fast(zacc[mt][nt][3] + ttv.w * b1v[nt]);
            store4bf(&t_w[hl * 72 + mt * 16 + q * 4], v0, v1, v2, v3);
        }
    }

    // P = Q^T T : M=32(j) x N=32(h2/wave) x K=64(m)
    f32x4 pacc[2][2] = {};
    const unsigned short* QT = (const unsigned short*)(ws + OFF_QT_BF);
    #pragma unroll
    for (int ks = 0; ks < 2; ks++) {
        bf16x8 bt[2];
        #pragma unroll
        for (int nt = 0; nt < 2; nt++)
            bt[nt] = *(const bf16x8*)(&t_w[(nt * 16 + l15) * 72 + ks * 32 + q * 8]);
        #pragma unroll
        for (int jt = 0; jt < 2; jt++) {
            bf16x8 aq = *(const bf16x8*)(QT + (jt * 16 + l15) * 64 + ks * 32 + q * 8);
            pacc[jt][0] = __builtin_amdgcn_mfma_f32_16x16x32_bf16(aq, bt[0], pacc[jt][0], 0, 0, 0);
            pacc[jt][1] = __builtin_amdgcn_mfma_f32_16x16x32_bf16(aq, bt[1], pacc[jt][1], 0, 0, 0);
        }
    }

    // pack P -> Ptout (wave-private bounce in pb_w = g_w region, dead after Z)
    {
        #pragma unroll
        for (int jt = 0; jt < 2; jt++)
            #pragma unroll
            for (int nt = 0; nt < 2; nt++) {
                int grp = (nt * 2 + (l15 >> 3)) & 3;
                #pragma unroll
                for (int r = 0; r < 4; r++) {
                    int lane8 = grp * 16 + q * 4 + r;
                    pb_w[(jt * 64 + lane8) * 8 + (l15 & 7)] = f2bf(pacc[jt][nt][r]);
                }
            }
        int hs = hblk * 4 + w;
        uint4 f0 = *(uint4*)(pb_w + (0 * 64 + lane) * 8);
        uint4 f1 = *(uint4*)(pb_w + (1 * 64 + lane) * 8);
        *(uint4*)(Ptout + (((size_t)(b * 32 + hs) * 2 + 0) * 64 + lane) * 8) = f0;
        *(uint4*)(Ptout + (((size_t)(b * 32 + hs) * 2 + 1) * 64 + lane) * 8) = f1;
    }
}

// ---------------------------------------------------------------------------
// K2F (final): Bn_val = P.W2 + y u (fp32); writes out1 directly and
// out0 = sum_n Bn_val*Phi_out. Grid 1024 1-D, XCD-swizzled (b = bid&127).
// ---------------------------------------------------------------------------
__global__ __launch_bounds__(256) void k2f_kernel(
        const unsigned short* __restrict__ Ptp,  // [B][32 hs][2 mt][64][8] bf16
        const unsigned short* __restrict__ W2p,  // frag-packed
        const float* __restrict__ y_init,        // [B][512]
        const float* __restrict__ ws,
        float* __restrict__ out)
{
    __shared__ __align__(16) float ls[4 * 544];
    __shared__ float phiout_s[NB * TT];

    const int t    = threadIdx.x;
    const int lane = t & 63;
    const int w    = t >> 6;
    const int q    = lane >> 4;
    const int l15  = lane & 15;
    const int bid  = blockIdx.x;
    const int b    = bid & 127;        // XCD affinity
    const int dblk = bid >> 7;         // 0..7
    const int dw   = dblk * 64 + w * 16;

    for (int f = t; f < NB * TT; f += 256) phiout_s[f] = ws[OFF_PHIOUT + f];

    f32x4 acc[2] = {};
    const unsigned short* Ab  = Ptp + (size_t)b * 32768;
    const unsigned short* W2b = W2p + (size_t)(dblk * 4 + w) * 16384;
    #pragma unroll 4
    for (int s = 0; s < 32; s++) {
        bf16x8 a0 = *(const bf16x8*)(Ab + (s * 2 + 0) * 512 + lane * 8);
        bf16x8 a1 = *(const bf16x8*)(Ab + (s * 2 + 1) * 512 + lane * 8);
        bf16x8 bb = *(const bf16x8*)(W2b + s * 512 + lane * 8);
        acc[0] = __builtin_amdgcn_mfma_f32_16x16x32_bf16(a0, bb, acc[0], 0, 0, 0);
        acc[1] = __builtin_amdgcn_mfma_f32_16x16x32_bf16(a1, bb, acc[1], 0, 0, 0);
    }

    const float* U = ws + OFF_U;
    float yv = y_init[(size_t)b * DD + dw + l15];
    #pragma unroll
    for (int mt = 0; mt < 2; mt++) {
        float4 uv = *(const float4*)(U + mt * 16 + q * 4);
        #pragma unroll
        for (int r = 0; r < 4; r++) {
            int j = mt * 16 + q * 4 + r;
            float uvr = (r == 0) ? uv.x : (r == 1) ? uv.y : (r == 2) ? uv.z : uv.w;
            ls[w * 544 + j * 17 + l15] = acc[mt][r] + yv * uvr;
        }
    }
    __syncthreads();

    // out1 = Bn copy (coalesced)
    float* out1 = out + (size_t)TT * BB * DD;
    #pragma unroll
    for (int it = 0; it < 8; it++) {
        int f = it * 64 + lane;
        int d_l = f >> 5, j2 = f & 31;
        out1[((size_t)b * DD + dw + d_l) * NB + j2] = ls[w * 544 + j2 * 17 + d_l];
    }

    // out0[t16, b, d] = sum_n val[d][n] * phiout[n][t16]   (64 d x 16 t per block)
    #pragma unroll
    for (int i = 0; i < 4; i++) {
        int idx = i * 256 + t;
        int t16 = idx >> 6, dl = idx & 63;
        float s = 0.f;
        #pragma unroll
        for (int n = 0; n < NB; n++)
            s += ls[(dl >> 4) * 544 + n * 17 + (dl & 15)] * phiout_s[n * TT + t16];
        out[(size_t)t16 * (BB * DD) + (size_t)b * DD + dblk * 64 + dl] = s;
    }
}

// ---------------------------------------------------------------------------
extern "C" void kernel_launch(void* const* d_in, const int* in_sizes, int n_in,
                              void* d_out, int out_size, void* d_ws, size_t ws_size,
                              hipStream_t stream) {
    const float* t_span = (const float*)d_in[0];
    const float* y_init = (const float*)d_in[1];
    const float* B_init = (const float*)d_in[2];
    const float* W1     = (const float*)d_in[3];
    const float* b1     = (const float*)d_in[4];
    const float* W2     = (const float*)d_in[5];
    float* ws  = (float*)d_ws;
    float* out = (float*)d_out;

    unsigned short* W1p  = (unsigned short*)(ws + OFF_W1P);
    unsigned short* W2p  = (unsigned short*)(ws + OFF_W2P);
    unsigned short* WWp  = (unsigned short*)(ws + OFF_WWP);
    float*          yW1  = ws + OFF_YW1;
    unsigned short* PtpA = (unsigned short*)(ws + OFF_PTPA);
    unsigned short* PtpB = (unsigned short*)(ws + OFF_PTP0);

    // ONE prologue dispatch: setup + pack_w1 + pack_w2 + pack_ww + yw1
    prologue_kernel<<<dim3(385), 256, 0, stream>>>(t_span, W1, W2, y_init, ws);

    k1_kernel<<<dim3(1024), 256, 0, stream>>>(B_init, W1p, b1, ws, PtpA);

    unsigned short* pin  = PtpA;
    unsigned short* pout = PtpB;
    for (int it = 1; it < ITERS; it++) {
        kf_kernel<<<dim3(1024), 256, 0, stream>>>(pin, WWp, yW1, b1, ws, pout);
        unsigned short* tmp = pin; pin = pout; pout = tmp;
    }
    // 9 kf's -> final P in pin
    k2f_kernel<<<dim3(1024), 256, 0, stream>>>(pin, W2p, y_init, ws, out);
}